// Round 4
// baseline (36.280 us; speedup 1.0000x reference)
//
#include <hip/hip_runtime.h>

#define N_HYP 128
#define BLOCK 256
#define WAVES 4  // BLOCK / 64

// Fused single-pass kernel. One wave per utterance (4/block). Lane owns
// j0=lane, j1=lane+64; k-loop via float4 LDS broadcasts; weight 1/(N-1-j)
// factored out. Block partial -> d_ws; last block (counter) reduces the
// 1024 partials and stores out[0]. No d_out memset needed (plain store).
__global__ __launch_bounds__(BLOCK) void margin_loss_fused(
    const float* __restrict__ scores, const int* __restrict__ werRank,
    float* __restrict__ partials, unsigned int* __restrict__ counter,
    float* __restrict__ out, int B, int nblocks) {
  __shared__ float s_lds[WAVES][N_HYP];
  __shared__ float wave_sum[WAVES];
  __shared__ bool amLast;

  const int tid  = threadIdx.x;
  const int lane = tid & 63;
  const int wid  = tid >> 6;
  const int u = blockIdx.x * WAVES + wid;
  const bool valid = (u < B);
  const size_t base = (size_t)(valid ? u : 0) * N_HYP;

  // Gather scores into WER-rank order (rank loads coalesced; score gather
  // within one 512B row -> L1-local).
  const int r0 = werRank[base + lane];
  const int r1 = werRank[base + lane + 64];
  const float sj0 = scores[base + r0];
  const float sj1 = scores[base + r1];
  s_lds[wid][lane]      = sj0;
  s_lds[wid][lane + 64] = sj1;
  // wave-local LDS row: compiler lgkmcnt orders write->read within the wave.

  const float4* srow = (const float4*)&s_lds[wid][0];
  float a0 = 0.f, b0 = 0.f, a1 = 0.f, b1 = 0.f;

  // k in [0,64): only the j0 term can be active (k > lane).
#pragma unroll
  for (int q = 0; q < 16; ++q) {
    const float4 sv = srow[q];
    const int k = q * 4;
    a0 += (k + 0 > lane) ? fmaxf(sv.x - sj0, 0.f) : 0.f;
    b0 += (k + 1 > lane) ? fmaxf(sv.y - sj0, 0.f) : 0.f;
    a0 += (k + 2 > lane) ? fmaxf(sv.z - sj0, 0.f) : 0.f;
    b0 += (k + 3 > lane) ? fmaxf(sv.w - sj0, 0.f) : 0.f;
  }
  // k in [64,128): j0 unconditional; j1 conditional on k-64 > lane.
#pragma unroll
  for (int q = 16; q < 32; ++q) {
    const float4 sv = srow[q];
    const int km = q * 4 - 64;
    a0 += fmaxf(sv.x - sj0, 0.f);
    b0 += fmaxf(sv.y - sj0, 0.f);
    a0 += fmaxf(sv.z - sj0, 0.f);
    b0 += fmaxf(sv.w - sj0, 0.f);
    a1 += (km + 0 > lane) ? fmaxf(sv.x - sj1, 0.f) : 0.f;
    b1 += (km + 1 > lane) ? fmaxf(sv.y - sj1, 0.f) : 0.f;
    a1 += (km + 2 > lane) ? fmaxf(sv.z - sj1, 0.f) : 0.f;
    b1 += (km + 3 > lane) ? fmaxf(sv.w - sj1, 0.f) : 0.f;
  }

  const float w0 = 1.0f / (float)(N_HYP - 1 - lane);        // j0 = lane
  const float w1 = (lane < 63) ? 1.0f / (float)(63 - lane)  // j1 = lane+64
                               : 0.0f;                      // j1 = 127: empty
  float val = (a0 + b0) * w0 + (a1 + b1) * w1;
  if (!valid) val = 0.f;

  for (int off = 32; off > 0; off >>= 1) val += __shfl_down(val, off, 64);
  if (lane == 0) wave_sum[wid] = val;
  __syncthreads();

  if (tid == 0) {
    const float bs = (wave_sum[0] + wave_sum[1]) + (wave_sum[2] + wave_sum[3]);
    partials[blockIdx.x] = bs;
    __threadfence();                                // device-scope release
    const unsigned prev = atomicAdd(counter, 1u);   // device-scope by default
    amLast = (prev == (unsigned)(nblocks - 1));
  }
  __syncthreads();

  if (amLast) {
    __threadfence();                                // acquire
    float v = 0.f;
    const int n4 = nblocks >> 2;
    const float4* p4 = (const float4*)partials;
    for (int i = tid; i < n4; i += BLOCK) {
      const float4 t = p4[i];
      v += (t.x + t.y) + (t.z + t.w);
    }
    for (int i = (nblocks & ~3) + tid; i < nblocks; i += BLOCK) v += partials[i];
    for (int off = 32; off > 0; off >>= 1) v += __shfl_down(v, off, 64);
    __syncthreads();  // wave_sum reuse
    if ((tid & 63) == 0) wave_sum[tid >> 6] = v;
    __syncthreads();
    if (tid == 0) out[0] = (wave_sum[0] + wave_sum[1]) + (wave_sum[2] + wave_sum[3]);
  }
}

extern "C" void kernel_launch(void* const* d_in, const int* in_sizes, int n_in,
                              void* d_out, int out_size, void* d_ws, size_t ws_size,
                              hipStream_t stream) {
  const float* scores  = (const float*)d_in[0];
  const int*   werRank = (const int*)d_in[2];
  float* out = (float*)d_out;
  const int B = in_sizes[0] / N_HYP;
  const int nblocks = (B + WAVES - 1) / WAVES;  // 1024 for B=4096

  float* partials = (float*)d_ws;
  unsigned int* counter = (unsigned int*)((char*)d_ws + ((nblocks * 4 + 255) & ~255));

  hipMemsetAsync(counter, 0, sizeof(unsigned int), stream);
  margin_loss_fused<<<nblocks, BLOCK, 0, stream>>>(scores, werRank, partials,
                                                   counter, out, B, nblocks);
}

// Round 5
// 17.557 us; speedup vs baseline: 2.0664x; 2.0664x over previous
//
#include <hip/hip_runtime.h>

#define N_HYP 128
#define BLOCK 256
#define WAVES 4  // BLOCK / 64

// k1: one wave per utterance, barrier-free. Scores loaded in NATURAL order
// (coalesced, independent of werRank load) -> LDS; permutation done as an
// LDS gather. This cuts the serial HBM chain from 2 dependent hops to 1.
// Lane owns j0=lane, j1=lane+64; k-loop via float4 LDS broadcasts; weight
// 1/(N-1-j) factored out of the pair loop. Per-WAVE partial store.
__global__ __launch_bounds__(BLOCK) void margin_loss_k1(
    const float* __restrict__ scores, const int* __restrict__ werRank,
    float* __restrict__ partials, int B) {
  __shared__ float s_nat[WAVES][N_HYP];
  __shared__ float s_rank[WAVES][N_HYP];

  const int tid  = threadIdx.x;
  const int lane = tid & 63;
  const int wid  = tid >> 6;
  const int u = blockIdx.x * WAVES + wid;
  const bool valid = (u < B);
  const size_t base = (size_t)(valid ? u : 0) * N_HYP;

  // Two INDEPENDENT coalesced global loads, issued back-to-back.
  const float2 sc = *(const float2*)&scores[base + 2 * lane];
  const int2   rk = *(const int2*)&werRank[base + 2 * lane];

  *(float2*)&s_nat[wid][2 * lane] = sc;
  // In-wave LDS ordering: compiler inserts lgkmcnt before dependent reads.
  const float g0 = s_nat[wid][rk.x];  // random within 512B row (~2-way, free)
  const float g1 = s_nat[wid][rk.y];
  *(float2*)&s_rank[wid][2 * lane] = make_float2(g0, g1);

  const float sj0 = s_rank[wid][lane];
  const float sj1 = s_rank[wid][lane + 64];

  const float4* srow = (const float4*)&s_rank[wid][0];
  float a0 = 0.f, b0 = 0.f, a1 = 0.f, b1 = 0.f;

  // k in [0,64): only the j0 term can be active (k > lane).
#pragma unroll
  for (int q = 0; q < 16; ++q) {
    const float4 sv = srow[q];
    const int k = q * 4;
    a0 += (k + 0 > lane) ? fmaxf(sv.x - sj0, 0.f) : 0.f;
    b0 += (k + 1 > lane) ? fmaxf(sv.y - sj0, 0.f) : 0.f;
    a0 += (k + 2 > lane) ? fmaxf(sv.z - sj0, 0.f) : 0.f;
    b0 += (k + 3 > lane) ? fmaxf(sv.w - sj0, 0.f) : 0.f;
  }
  // k in [64,128): j0 unconditional; j1 conditional on k-64 > lane.
#pragma unroll
  for (int q = 16; q < 32; ++q) {
    const float4 sv = srow[q];
    const int km = q * 4 - 64;
    a0 += fmaxf(sv.x - sj0, 0.f);
    b0 += fmaxf(sv.y - sj0, 0.f);
    a0 += fmaxf(sv.z - sj0, 0.f);
    b0 += fmaxf(sv.w - sj0, 0.f);
    a1 += (km + 0 > lane) ? fmaxf(sv.x - sj1, 0.f) : 0.f;
    b1 += (km + 1 > lane) ? fmaxf(sv.y - sj1, 0.f) : 0.f;
    a1 += (km + 2 > lane) ? fmaxf(sv.z - sj1, 0.f) : 0.f;
    b1 += (km + 3 > lane) ? fmaxf(sv.w - sj1, 0.f) : 0.f;
  }

  const float w0 = 1.0f / (float)(N_HYP - 1 - lane);        // j0 = lane
  const float w1 = (lane < 63) ? 1.0f / (float)(63 - lane)  // j1 = lane+64
                               : 0.0f;                      // j1 = 127: empty
  float val = (a0 + b0) * w0 + (a1 + b1) * w1;

  for (int off = 32; off > 0; off >>= 1) val += __shfl_down(val, off, 64);
  if (lane == 0 && valid) partials[u] = val;  // per-wave partial, no barrier
}

// k2: single wave, shuffle-only reduce of B per-wave partials.
__global__ __launch_bounds__(64) void margin_loss_k2(
    const float* __restrict__ p, int n, float* __restrict__ out) {
  float v = 0.f;
  const int n4 = n >> 2;
  const float4* p4 = (const float4*)p;
  for (int i = threadIdx.x; i < n4; i += 64) {
    const float4 t = p4[i];
    v += (t.x + t.y) + (t.z + t.w);
  }
  for (int i = (n & ~3) + threadIdx.x; i < n; i += 64) v += p[i];
  for (int off = 32; off > 0; off >>= 1) v += __shfl_down(v, off, 64);
  if (threadIdx.x == 0) out[0] = v;
}

extern "C" void kernel_launch(void* const* d_in, const int* in_sizes, int n_in,
                              void* d_out, int out_size, void* d_ws, size_t ws_size,
                              hipStream_t stream) {
  const float* scores  = (const float*)d_in[0];
  const int*   werRank = (const int*)d_in[2];
  float* out = (float*)d_out;
  float* partials = (float*)d_ws;
  const int B = in_sizes[0] / N_HYP;

  const int nblocks = (B + WAVES - 1) / WAVES;  // 1024 for B=4096
  margin_loss_k1<<<nblocks, BLOCK, 0, stream>>>(scores, werRank, partials, B);
  margin_loss_k2<<<1, 64, 0, stream>>>(partials, B, out);
}

// Round 6
// 13.915 us; speedup vs baseline: 2.6073x; 1.2618x over previous
//
#include <hip/hip_runtime.h>

#define N_HYP 128
#define BLOCK 256
#define WAVES 4  // BLOCK / 64

// k1: one wave per utterance, barrier-free. Scores loaded in NATURAL order
// (coalesced, independent of the werRank load) -> LDS; permutation done as
// an LDS gather (1 HBM round-trip instead of 2 dependent ones).
// Lane owns j0=lane, j1=lane+64; k-loop via float4 LDS broadcasts; weight
// 1/(N-1-j) factored out. Per-WAVE partial store (no __syncthreads at all).
__global__ __launch_bounds__(BLOCK) void margin_loss_k1(
    const float* __restrict__ scores, const int* __restrict__ werRank,
    float* __restrict__ partials, int B) {
  __shared__ float s_nat[WAVES][N_HYP];
  __shared__ float s_rank[WAVES][N_HYP];

  const int tid  = threadIdx.x;
  const int lane = tid & 63;
  const int wid  = tid >> 6;
  const int u = blockIdx.x * WAVES + wid;
  const bool valid = (u < B);
  const size_t base = (size_t)(valid ? u : 0) * N_HYP;

  // Two INDEPENDENT coalesced global loads, issued back-to-back.
  const float2 sc = *(const float2*)&scores[base + 2 * lane];
  const int2   rk = *(const int2*)&werRank[base + 2 * lane];

  *(float2*)&s_nat[wid][2 * lane] = sc;
  // In-wave LDS ordering: compiler inserts lgkmcnt before dependent reads.
  const float g0 = s_nat[wid][rk.x];  // random within 512B row (~2-way, free)
  const float g1 = s_nat[wid][rk.y];
  *(float2*)&s_rank[wid][2 * lane] = make_float2(g0, g1);

  const float sj0 = s_rank[wid][lane];
  const float sj1 = s_rank[wid][lane + 64];

  const float4* srow = (const float4*)&s_rank[wid][0];
  float a0 = 0.f, b0 = 0.f, a1 = 0.f, b1 = 0.f;

  // k in [0,64): only the j0 term can be active (k > lane).
#pragma unroll
  for (int q = 0; q < 16; ++q) {
    const float4 sv = srow[q];
    const int k = q * 4;
    a0 += (k + 0 > lane) ? fmaxf(sv.x - sj0, 0.f) : 0.f;
    b0 += (k + 1 > lane) ? fmaxf(sv.y - sj0, 0.f) : 0.f;
    a0 += (k + 2 > lane) ? fmaxf(sv.z - sj0, 0.f) : 0.f;
    b0 += (k + 3 > lane) ? fmaxf(sv.w - sj0, 0.f) : 0.f;
  }
  // k in [64,128): j0 unconditional; j1 conditional on k-64 > lane.
#pragma unroll
  for (int q = 16; q < 32; ++q) {
    const float4 sv = srow[q];
    const int km = q * 4 - 64;
    a0 += fmaxf(sv.x - sj0, 0.f);
    b0 += fmaxf(sv.y - sj0, 0.f);
    a0 += fmaxf(sv.z - sj0, 0.f);
    b0 += fmaxf(sv.w - sj0, 0.f);
    a1 += (km + 0 > lane) ? fmaxf(sv.x - sj1, 0.f) : 0.f;
    b1 += (km + 1 > lane) ? fmaxf(sv.y - sj1, 0.f) : 0.f;
    a1 += (km + 2 > lane) ? fmaxf(sv.z - sj1, 0.f) : 0.f;
    b1 += (km + 3 > lane) ? fmaxf(sv.w - sj1, 0.f) : 0.f;
  }

  const float w0 = 1.0f / (float)(N_HYP - 1 - lane);        // j0 = lane
  const float w1 = (lane < 63) ? 1.0f / (float)(63 - lane)  // j1 = lane+64
                               : 0.0f;                      // j1 = 127: empty
  float val = (a0 + b0) * w0 + (a1 + b1) * w1;

  for (int off = 32; off > 0; off >>= 1) val += __shfl_down(val, off, 64);
  if (lane == 0 && valid) partials[u] = val;  // per-wave partial, no barrier
}

// k2: ONE 1024-thread block; each thread loads exactly one float4 (4096
// partials = 1024 float4s) -> all loads in flight at once, ONE memory
// round-trip. Shuffle-reduce, 16 wave sums via LDS, wave 0 finishes.
__global__ __launch_bounds__(1024) void margin_loss_k2(
    const float* __restrict__ p, int n, float* __restrict__ out) {
  const int tid = threadIdx.x;
  const int n4 = n >> 2;
  const float4* p4 = (const float4*)p;
  float v = 0.f;
  for (int i = tid; i < n4; i += 1024) {
    const float4 t = p4[i];
    v += (t.x + t.y) + (t.z + t.w);
  }
  for (int i = (n & ~3) + tid; i < n; i += 1024) v += p[i];  // tail (unused for B=4096)

  for (int off = 32; off > 0; off >>= 1) v += __shfl_down(v, off, 64);
  __shared__ float ws[16];
  if ((tid & 63) == 0) ws[tid >> 6] = v;
  __syncthreads();
  if (tid < 64) {
    float w = (tid < 16) ? ws[tid] : 0.f;
    for (int off = 8; off > 0; off >>= 1) w += __shfl_down(w, off, 64);
    if (tid == 0) out[0] = w;
  }
}

extern "C" void kernel_launch(void* const* d_in, const int* in_sizes, int n_in,
                              void* d_out, int out_size, void* d_ws, size_t ws_size,
                              hipStream_t stream) {
  const float* scores  = (const float*)d_in[0];
  const int*   werRank = (const int*)d_in[2];
  float* out = (float*)d_out;
  float* partials = (float*)d_ws;
  const int B = in_sizes[0] / N_HYP;

  const int nblocks = (B + WAVES - 1) / WAVES;  // 1024 for B=4096
  margin_loss_k1<<<nblocks, BLOCK, 0, stream>>>(scores, werRank, partials, B);
  margin_loss_k2<<<1, 1024, 0, stream>>>(partials, B, out);
}